// Round 1
// baseline (195.033 us; speedup 1.0000x reference)
//
#include <hip/hip_runtime.h>
#include <stdint.h>
#include <math.h>

#define B_    16
#define CIN   64
#define NPT   8192
#define COUT  128
#define NRING 8
#define EPSV  1e-5f

typedef unsigned int uint32;
typedef unsigned long long ull;

// monotone order-preserving float->uint key (for atomicMax/Min on floats)
__device__ __forceinline__ uint32 fkey(float f) {
  uint32 u = __float_as_uint(f);
  return (u & 0x80000000u) ? ~u : (u | 0x80000000u);
}
__device__ __forceinline__ float kinv(uint32 k) {
  uint32 u = (k & 0x80000000u) ? (k ^ 0x80000000u) : ~k;
  return __uint_as_float(u);
}

// ---------------------------------------------------------------------------
// k_pre: blocks 0..15  -> per-batch ring histogram (ballot-aggregated)
//        blocks 16..31 -> init sums/ssums/mxkey/mnkey
//        blocks 32..95 -> transpose W[r][c][k] -> Wt[r][k][c]
// ---------------------------------------------------------------------------
__global__ __launch_bounds__(256) void k_pre(
    const float* __restrict__ W, const int* __restrict__ ring,
    float* __restrict__ Wt, uint32* __restrict__ counts,
    float* __restrict__ sums, float* __restrict__ ssums,
    uint32* __restrict__ mxkey, uint32* __restrict__ mnkey)
{
  int tid = threadIdx.x;
  int blk = blockIdx.x;
  if (blk < 16) {
    int b = blk;
    int lane = tid & 63;
    int cntv = 0;  // lane<8 accumulates count for ring==lane (per wave)
    for (int n = tid; n < NPT; n += 256) {
      int rl = ring[b * NPT + n];
      #pragma unroll
      for (int rr = 0; rr < NRING; ++rr) {
        ull m = __ballot(rl == rr);
        if (lane == rr) cntv += (int)__popcll(m);
      }
    }
    __shared__ uint32 h8[NRING];
    if (tid < NRING) h8[tid] = 0u;
    __syncthreads();
    if (lane < NRING) atomicAdd(&h8[lane], (uint32)cntv);
    __syncthreads();
    if (tid < NRING) counts[b * NRING + tid] = h8[tid];
  } else if (blk < 32) {
    int idx0 = (blk - 16) * 256 + tid;
    for (int idx = idx0; idx < B_ * NRING * COUT; idx += 16 * 256) {
      mxkey[idx] = 0u;
      mnkey[idx] = 0xFFFFFFFFu;
      if (idx < NRING * COUT) { sums[idx] = 0.f; ssums[idx] = 0.f; }
    }
  } else {
    int idx0 = (blk - 32) * 1024 + tid;
    #pragma unroll
    for (int i = 0; i < 4; ++i) {
      int idx = idx0 + i * 256;              // idx = (r*64 + k)*128 + c
      int c = idx & 127;
      int k = (idx >> 7) & 63;
      int r = idx >> 13;
      Wt[idx] = W[(r * COUT + c) * CIN + k];
    }
  }
}

// ---------------------------------------------------------------------------
// k_prefix: per-batch exclusive prefix over ring counts -> segment bases,
//           plus global per-ring totals. 1 block.
// ---------------------------------------------------------------------------
__global__ void k_prefix(const uint32* __restrict__ counts,
                         uint32* __restrict__ baseArr, uint32* __restrict__ cursor,
                         uint32* __restrict__ ringtot)
{
  int tid = threadIdx.x;
  if (tid < B_ * NRING) {
    int b = tid >> 3, r = tid & 7;
    uint32 s = 0;
    for (int rp = 0; rp < r; ++rp) s += counts[b * NRING + rp];
    uint32 bas = (uint32)(b * NPT) + s;
    baseArr[tid] = bas;
    cursor[tid]  = bas;
  }
  if (tid < NRING) {
    uint32 t = 0;
    for (int b = 0; b < B_; ++b) t += counts[b * NRING + tid];
    ringtot[tid] = t;
  }
}

// ---------------------------------------------------------------------------
// k_scatter: counting-sort gather. Reads x coalesced (lane = n, k-loop),
// writes each point's 256B row to its (batch,ring)-sorted slot in xs
// (xs lives in the front half of d_out — consumed by k_main before k_bcast
// overwrites d_out).
// ---------------------------------------------------------------------------
__global__ __launch_bounds__(256) void k_scatter(
    const float* __restrict__ x, const int* __restrict__ ring,
    uint32* __restrict__ cursor, float* __restrict__ xs)
{
  int gtid = blockIdx.x * 256 + threadIdx.x;   // 0 .. B*N-1
  int b = gtid >> 13;
  int n = gtid & (NPT - 1);
  int lane = threadIdx.x & 63;
  int rl = ring[b * NPT + n];
  uint32 pos = 0;
  #pragma unroll
  for (int rr = 0; rr < NRING; ++rr) {
    ull m = __ballot(rl == rr);                 // convergent
    if (rl == rr) {
      int leader = __builtin_ctzll(m);
      uint32 base = 0;
      if (lane == leader)
        base = atomicAdd(&cursor[b * NRING + rr], (uint32)__popcll(m));
      base = (uint32)__shfl((int)base, leader, 64);
      pos = base + (uint32)__popcll(m & ((1ull << lane) - 1ull));
    }
  }
  const float* xb = x + (size_t)b * CIN * NPT + n;
  float* dst = xs + (size_t)pos * CIN;
  #pragma unroll
  for (int k4 = 0; k4 < CIN; k4 += 4) {
    float4 v;
    v.x = xb[(size_t)(k4 + 0) * NPT];
    v.y = xb[(size_t)(k4 + 1) * NPT];
    v.z = xb[(size_t)(k4 + 2) * NPT];
    v.w = xb[(size_t)(k4 + 3) * NPT];
    *reinterpret_cast<float4*>(dst + k4) = v;
  }
}

// ---------------------------------------------------------------------------
// k_main: hot kernel. 512 blocks = (b, r, part/4) of a (batch,ring) segment.
// 8 waves/block; wave w owns channels [w*16, w*16+16). Ring r is block-
// uniform -> W rows are wave-uniform -> scalar (SGPR) loads; x staged in LDS
// with pad-65 rows (conflict-free ds_read_b32). Bias dropped (cancels in BN).
// Accumulates per-(r,c) sum/sumsq and per-(b,r,c) max/min of z = W·x.
// ---------------------------------------------------------------------------
__global__ __launch_bounds__(512, 4) void k_main(
    const float* __restrict__ xs, const float* __restrict__ Wt,
    const uint32* __restrict__ baseArr, const uint32* __restrict__ counts,
    float* __restrict__ sums, float* __restrict__ ssums,
    uint32* __restrict__ mxkey, uint32* __restrict__ mnkey)
{
  int blk = blockIdx.x;               // b*32 + r*4 + part
  int part = blk & 3;
  int r = (blk >> 2) & 7;
  int b = blk >> 5;
  uint32 segBase = baseArr[b * NRING + r];
  uint32 segCnt  = counts[b * NRING + r];
  uint32 per = (segCnt + 3) >> 2;
  uint32 s0 = min((uint32)part * per, segCnt);
  uint32 s1 = min(s0 + per, segCnt);

  int tid = threadIdx.x;
  int lane = tid & 63;
  int w = __builtin_amdgcn_readfirstlane(tid >> 6);  // wave id, force SGPR
  int c0 = w * 16;
  const float* WtR = Wt + (size_t)r * CIN * COUT + c0;  // uniform

  __shared__ float xl[64 * 65];

  float sum_r[16], ss_r[16], mx_r[16], mn_r[16];
  #pragma unroll
  for (int c = 0; c < 16; ++c) {
    sum_r[c] = 0.f; ss_r[c] = 0.f;
    mx_r[c] = -__builtin_inff(); mn_r[c] = __builtin_inff();
  }

  for (uint32 g = s0; g < s1; g += 64) {
    uint32 gc = min(64u, s1 - g);
    // stage up to 64 point-rows (zero-fill tail), b32 LDS writes (pad 65)
    for (int j = tid; j < 1024; j += 512) {
      int p = j >> 4;
      int k4 = (j & 15) << 2;
      float4 v = make_float4(0.f, 0.f, 0.f, 0.f);
      if ((uint32)p < gc)
        v = *reinterpret_cast<const float4*>(xs + (size_t)(segBase + g + p) * CIN + k4);
      xl[p * 65 + k4 + 0] = v.x;
      xl[p * 65 + k4 + 1] = v.y;
      xl[p * 65 + k4 + 2] = v.z;
      xl[p * 65 + k4 + 3] = v.w;
    }
    __syncthreads();

    float acc[16];
    #pragma unroll
    for (int c = 0; c < 16; ++c) acc[c] = 0.f;
    const float* xrow = xl + lane * 65;
    #pragma unroll 8
    for (int k = 0; k < CIN; ++k) {
      float xv = xrow[k];                       // 1 ds_read_b32, 2-way free
      const float* wk = WtR + k * COUT;         // uniform -> s_load
      #pragma unroll
      for (int c = 0; c < 16; ++c) acc[c] = fmaf(wk[c], xv, acc[c]);
    }

    if (gc == 64u) {
      #pragma unroll
      for (int c = 0; c < 16; ++c) {
        float y = acc[c];
        sum_r[c] += y;
        ss_r[c] = fmaf(y, y, ss_r[c]);
        mx_r[c] = fmaxf(mx_r[c], y);
        mn_r[c] = fminf(mn_r[c], y);
      }
    } else {
      bool valid = (uint32)lane < gc;
      #pragma unroll
      for (int c = 0; c < 16; ++c) {
        float y = valid ? acc[c] : 0.f;
        sum_r[c] += y;
        ss_r[c] = fmaf(y, y, ss_r[c]);
        mx_r[c] = fmaxf(mx_r[c], valid ? acc[c] : -__builtin_inff());
        mn_r[c] = fminf(mn_r[c], valid ? acc[c] :  __builtin_inff());
      }
    }
    __syncthreads();
  }

  // one cross-lane reduction per block, then few atomics
  #pragma unroll
  for (int c = 0; c < 16; ++c) {
    float s = sum_r[c], q = ss_r[c], M = mx_r[c], m = mn_r[c];
    #pragma unroll
    for (int off = 32; off > 0; off >>= 1) {
      s += __shfl_xor(s, off, 64);
      q += __shfl_xor(q, off, 64);
      M = fmaxf(M, __shfl_xor(M, off, 64));
      m = fminf(m, __shfl_xor(m, off, 64));
    }
    if (lane == 0) {
      atomicAdd(&sums [r * COUT + c0 + c], s);
      atomicAdd(&ssums[r * COUT + c0 + c], q);
      atomicMax(&mxkey[(b * NRING + r) * COUT + c0 + c], fkey(M));
      atomicMin(&mnkey[(b * NRING + r) * COUT + c0 + c], fkey(m));
    }
  }
}

// ---------------------------------------------------------------------------
// k_final: per (b,r,c) compute BN-affine of the segment max.
// yn = (z - mean_z)*gamma*invstd + beta ; pick zmax/zmin by sign of scale.
// ---------------------------------------------------------------------------
__global__ __launch_bounds__(256) void k_final(
    const float* __restrict__ sums, const float* __restrict__ ssums,
    const uint32* __restrict__ ringtot,
    const uint32* __restrict__ mxkey, const uint32* __restrict__ mnkey,
    const float* __restrict__ gamma, const float* __restrict__ beta,
    float* __restrict__ mxout)
{
  int idx = blockIdx.x * 256 + threadIdx.x;   // (b*8 + r)*128 + c
  int c = idx & 127;
  int r = (idx >> 7) & 7;
  float cnt  = fmaxf((float)ringtot[r], 1.f);
  float mean = sums[r * COUT + c] / cnt;
  float var  = ssums[r * COUT + c] / cnt - mean * mean;
  var = fmaxf(var, 0.f);
  float inv = 1.f / sqrtf(var + EPSV);
  float a   = gamma[r * COUT + c] * inv;
  float bet = beta[r * COUT + c];
  float zmax = kinv(mxkey[idx]);
  float zmin = kinv(mnkey[idx]);
  mxout[idx] = (a >= 0.f) ? fmaf(a, zmax - mean, bet)
                          : fmaf(a, zmin - mean, bet);
}

// ---------------------------------------------------------------------------
// k_bcast: out[b][c][n] = mxout[b][ring[b][n]][c]. LUT staged in LDS at
// stride 129 (bank-conflict-free), fully coalesced 256B/wave stores.
// ---------------------------------------------------------------------------
__global__ __launch_bounds__(256) void k_bcast(
    const int* __restrict__ ring, const float* __restrict__ mxout,
    float* __restrict__ out)
{
  __shared__ float mxl[NRING * 129];
  int tid = threadIdx.x;
  int chunk0 = blockIdx.x * 4;         // 4 wave-chunks of 64 n's per block
  int b = chunk0 >> 7;                 // 128 chunks per batch (block-uniform)
  for (int j = tid; j < NRING * COUT; j += 256) {
    int rr = j >> 7, cc = j & 127;
    mxl[rr * 129 + cc] = mxout[b * NRING * COUT + j];
  }
  __syncthreads();
  int wv = tid >> 6, lane = tid & 63;
  int chunk = chunk0 + wv;
  int n = (chunk & 127) * 64 + lane;
  int rl = ring[b * NPT + n];
  float* ob = out + (size_t)b * COUT * NPT + n;
  int roff = rl * 129;
  #pragma unroll 8
  for (int c = 0; c < COUT; ++c) {
    ob[(size_t)c * NPT] = mxl[roff + c];   // broadcast/≤8-addr read, no conflict
  }
}

// ---------------------------------------------------------------------------
extern "C" void kernel_launch(void* const* d_in, const int* in_sizes, int n_in,
                              void* d_out, int out_size, void* d_ws, size_t ws_size,
                              hipStream_t stream)
{
  const float* x     = (const float*)d_in[0];
  const int*   ring  = (const int*)  d_in[1];
  const float* W     = (const float*)d_in[2];
  // d_in[3] (conv bias) provably cancels in BatchNorm -> unused
  const float* gamma = (const float*)d_in[4];
  const float* beta  = (const float*)d_in[5];
  float* out = (float*)d_out;

  // ws layout (~465 KB)
  float*  Wt      = (float*)d_ws;                 // 65536 f
  uint32* counts  = (uint32*)(Wt + 65536);        // 128
  uint32* baseArr = counts + 128;                 // 128
  uint32* cursor  = baseArr + 128;                // 128
  uint32* ringtot = cursor + 128;                 // 8
  float*  sums    = (float*)(ringtot + 8);        // 1024
  float*  ssums   = sums + 1024;                  // 1024
  uint32* mxkey   = (uint32*)(ssums + 1024);      // 16384
  uint32* mnkey   = mxkey + 16384;                // 16384
  float*  mxout   = (float*)(mnkey + 16384);      // 16384

  // ring-sorted x copy lives in d_out's front half; consumed by k_main
  // strictly before k_bcast overwrites d_out.
  float* xs = out;

  k_pre    <<<dim3(96),  dim3(256), 0, stream>>>(W, ring, Wt, counts, sums, ssums, mxkey, mnkey);
  k_prefix <<<dim3(1),   dim3(128), 0, stream>>>(counts, baseArr, cursor, ringtot);
  k_scatter<<<dim3(512), dim3(256), 0, stream>>>(x, ring, cursor, xs);
  k_main   <<<dim3(512), dim3(512), 0, stream>>>(xs, Wt, baseArr, counts, sums, ssums, mxkey, mnkey);
  k_final  <<<dim3(64),  dim3(256), 0, stream>>>(sums, ssums, ringtot, mxkey, mnkey, gamma, beta, mxout);
  k_bcast  <<<dim3(512), dim3(256), 0, stream>>>(ring, mxout, out);
}